// Round 1
// baseline (689.177 us; speedup 1.0000x reference)
//
#include <hip/hip_runtime.h>

// ---------------------------------------------------------------------------
// GCN_35107062677929: 3-layer GCN, N=50000, E=800000, D=128, fp32.
//
// Pipeline (A = normalized adjacency with self-loops, shared by all convs):
//   g0 = dis .* lrelu(x @ W_in + b_in)                 [N,128]
//   a0[i] = dis[i]*(sum_{s->i} g0[s] + g0[i])          [N,128]   (= A h0)
//   h1 = lrelu(a0 @ W1 + b1)                           [N,256]
//   g2 = dis .* (h1 @ W2)                              [N,128]
//   h2 = lrelu(dis[i]*(sum g2[s] + g2[i]) + b2)        [N,128]
//   g3 = dis .* (h2 @ W3)                              [N,64]
//   out[i] = (lrelu(dis[i]*(sum g3 + g3[i]) + b3)) @ W_out + b_out   [N,1]
// CSR (in-edges) built once per launch; no float atomics anywhere.
// ---------------------------------------------------------------------------

#define LRELU(v) ((v) > 0.f ? (v) : 0.01f * (v))

__global__ __launch_bounds__(256) void k_count(const int* __restrict__ dst,
                                               int* __restrict__ cnt, int E) {
  int e = blockIdx.x * 256 + threadIdx.x;
  if (e < E) atomicAdd(&cnt[dst[e]], 1);
}

__global__ __launch_bounds__(256) void k_dis(const int* __restrict__ cnt,
                                             float* __restrict__ dis, int N) {
  int i = blockIdx.x * 256 + threadIdx.x;
  if (i < N) dis[i] = rsqrtf((float)cnt[i] + 1.0f);  // +1 self-loop
}

// single-block exclusive scan of cnt[0..N) -> offs, offs[N]=E
__global__ __launch_bounds__(1024) void k_scan(const int* __restrict__ cnt,
                                               int* __restrict__ offs, int N, int E) {
  constexpr int T = 1024;
  __shared__ int ssum[T];
  int t = threadIdx.x;
  int chunk = (N + T - 1) / T;
  int b0 = t * chunk;
  int local = 0;
  for (int j = 0; j < chunk; ++j) {
    int idx = b0 + j;
    if (idx < N) local += cnt[idx];
  }
  ssum[t] = local;
  __syncthreads();
  for (int off = 1; off < T; off <<= 1) {
    int v = (t >= off) ? ssum[t - off] : 0;
    __syncthreads();
    ssum[t] += v;
    __syncthreads();
  }
  int run = (t > 0) ? ssum[t - 1] : 0;
  for (int j = 0; j < chunk; ++j) {
    int idx = b0 + j;
    if (idx < N) { offs[idx] = run; run += cnt[idx]; }
  }
  if (t == 0) offs[N] = E;
}

__global__ __launch_bounds__(256) void k_fill(const int* __restrict__ src,
                                              const int* __restrict__ dst,
                                              const int* __restrict__ offs,
                                              int* __restrict__ cur,
                                              int* __restrict__ esrc, int E) {
  int e = blockIdx.x * 256 + threadIdx.x;
  if (e < E) {
    int d = dst[e];
    int pos = offs[d] + atomicAdd(&cur[d], 1);
    esrc[pos] = src[e];
  }
}

// ---------------------------------------------------------------------------
// GEMM: [M,K] @ [K,F] + epilogue. 64-row tile in LDS, 256 threads,
// per-thread micro-tile 8 rows x (F/32) cols.
// EPI 0: out = dis[row] * lrelu(acc + b[col])
// EPI 1: out = lrelu(acc + b[col])
// EPI 2: out = dis[row] * acc
// ---------------------------------------------------------------------------
template <int K, int F, int EPI>
__global__ __launch_bounds__(256) void k_gemm(const float* __restrict__ X,
                                              const float* __restrict__ W,
                                              const float* __restrict__ b,
                                              const float* __restrict__ dis,
                                              float* __restrict__ out, int M) {
  constexpr int TM = 64;
  constexpr int C = F / 32;
  __shared__ float xs[TM * K];
  const int m0 = blockIdx.x * TM;
  const int tid = threadIdx.x;

  // stage 64 x K contiguous tile (rows are contiguous, stride K)
  {
    const float4* xg = (const float4*)X;
    float4* xs4 = (float4*)xs;
    const int base4 = m0 * (K / 4);
    const int total4 = TM * (K / 4);
    const int limit4 = M * (K / 4);
    for (int idx = tid; idx < total4; idx += 256) {
      float4 v = {0.f, 0.f, 0.f, 0.f};
      if (base4 + idx < limit4) v = xg[base4 + idx];
      xs4[idx] = v;
    }
  }
  __syncthreads();

  const int tc = tid & 31;   // col group
  const int tr = tid >> 5;   // row group (0..7)

  float acc[8][C];
#pragma unroll
  for (int j = 0; j < 8; ++j)
#pragma unroll
    for (int c = 0; c < C; ++c) acc[j][c] = 0.f;

  for (int k = 0; k < K; k += 4) {
    float4 xv[8];
#pragma unroll
    for (int j = 0; j < 8; ++j)
      xv[j] = *(const float4*)&xs[(tr * 8 + j) * K + k];
#pragma unroll
    for (int kk = 0; kk < 4; ++kk) {
      float wv[C];
      const float* wrow = &W[(k + kk) * F + tc * C];
      if constexpr (C == 2) {
        float2 t = *(const float2*)wrow;
        wv[0] = t.x; wv[1] = t.y;
      } else if constexpr (C == 4) {
        float4 t = *(const float4*)wrow;
        wv[0] = t.x; wv[1] = t.y; wv[2] = t.z; wv[3] = t.w;
      } else {  // C == 8
        float4 t0 = *(const float4*)wrow;
        float4 t1 = *(const float4*)(wrow + 4);
        wv[0] = t0.x; wv[1] = t0.y; wv[2] = t0.z; wv[3] = t0.w;
        wv[4] = t1.x; wv[5] = t1.y; wv[6] = t1.z; wv[7] = t1.w;
      }
#pragma unroll
      for (int j = 0; j < 8; ++j) {
        const float xval = ((const float*)&xv[j])[kk];
#pragma unroll
        for (int c = 0; c < C; ++c) acc[j][c] += xval * wv[c];
      }
    }
  }

#pragma unroll
  for (int j = 0; j < 8; ++j) {
    const int row = m0 + tr * 8 + j;
    if (row < M) {
      float dv = 1.f;
      if constexpr (EPI != 1) dv = dis[row];
#pragma unroll
      for (int c = 0; c < C; ++c) {
        const int col = tc * C + c;
        float v = acc[j][c];
        if constexpr (EPI == 0) { v += b[col]; v = LRELU(v); v *= dv; }
        if constexpr (EPI == 1) { v += b[col]; v = LRELU(v); }
        if constexpr (EPI == 2) { v *= dv; }
        out[row * F + col] = v;
      }
    }
  }
}

// ---------------------------------------------------------------------------
// Aggregation: one wave per node. out[i] = dis[i]*(sum_{s->i} G[s] + G[i])
// MODE 0: plain (write dis[i]*acc)
// MODE 1: h = lrelu(dis[i]*acc + b[col])
// F == 128, lane handles 2 consecutive cols (float2 gathers).
// ---------------------------------------------------------------------------
template <int MODE>
__global__ __launch_bounds__(256) void k_agg128(const float* __restrict__ G,
                                                const int* __restrict__ esrc,
                                                const int* __restrict__ offs,
                                                const float* __restrict__ dis,
                                                const float* __restrict__ b,
                                                float* __restrict__ out, int N) {
  const int wid = (blockIdx.x * 256 + threadIdx.x) >> 6;
  const int lane = threadIdx.x & 63;
  if (wid >= N) return;
  const int i = wid;
  const int col = lane * 2;
  float2 acc = *(const float2*)&G[(long)i * 128 + col];  // self term
  const int e0 = offs[i], e1 = offs[i + 1];
  for (int e = e0; e < e1; ++e) {
    const int s = esrc[e];
    const float2 gv = *(const float2*)&G[(long)s * 128 + col];
    acc.x += gv.x;
    acc.y += gv.y;
  }
  const float dv = dis[i];
  float vx = acc.x * dv, vy = acc.y * dv;
  if constexpr (MODE == 1) {
    vx += b[col];     vx = LRELU(vx);
    vy += b[col + 1]; vy = LRELU(vy);
  }
  *(float2*)&out[(long)i * 128 + col] = make_float2(vx, vy);
}

// Final: agg over g3 (F=64, lane=col) fused with h3 @ W_out + b_out.
__global__ __launch_bounds__(256) void k_agg_final(const float* __restrict__ G,
                                                   const int* __restrict__ esrc,
                                                   const int* __restrict__ offs,
                                                   const float* __restrict__ dis,
                                                   const float* __restrict__ b3,
                                                   const float* __restrict__ Wout,
                                                   const float* __restrict__ bout,
                                                   float* __restrict__ out, int N) {
  const int wid = (blockIdx.x * 256 + threadIdx.x) >> 6;
  const int lane = threadIdx.x & 63;
  if (wid >= N) return;
  const int i = wid;
  float acc = G[(long)i * 64 + lane];  // self
  const int e0 = offs[i], e1 = offs[i + 1];
  for (int e = e0; e < e1; ++e) {
    const int s = esrc[e];
    acc += G[(long)s * 64 + lane];
  }
  float v = acc * dis[i] + b3[lane];
  v = LRELU(v);
  v *= Wout[lane];
#pragma unroll
  for (int off = 32; off > 0; off >>= 1) v += __shfl_down(v, off);
  if (lane == 0) out[i] = v + bout[0];
}

// ---------------------------------------------------------------------------

extern "C" void kernel_launch(void* const* d_in, const int* in_sizes, int n_in,
                              void* d_out, int out_size, void* d_ws, size_t ws_size,
                              hipStream_t stream) {
  const float* x     = (const float*)d_in[0];
  const int* eidx    = (const int*)d_in[1];
  const float* W_in  = (const float*)d_in[2];
  const float* b_in  = (const float*)d_in[3];
  const float* W1    = (const float*)d_in[4];
  const float* b1    = (const float*)d_in[5];
  const float* W2    = (const float*)d_in[6];
  const float* b2    = (const float*)d_in[7];
  const float* W3    = (const float*)d_in[8];
  const float* b3    = (const float*)d_in[9];
  const float* W_out = (const float*)d_in[10];
  const float* b_out = (const float*)d_in[11];
  float* out = (float*)d_out;

  const int N = in_sizes[0] / 128;
  const int E = in_sizes[1] / 2;
  const int* src = eidx;
  const int* dst = eidx + E;

  // workspace layout (all 4-byte elems, 16B-aligned sections)
  int* ws_i    = (int*)d_ws;
  int* cnt     = ws_i;                 // N
  int* cur     = ws_i + N;             // N
  int* offs    = ws_i + 2 * N;         // N+1 (padded to N+4)
  int* esrc    = ws_i + 3 * N + 4;     // E
  float* dis   = (float*)(ws_i + 3 * N + 4 + E);  // N
  float* buf1  = dis + N;              // N*128  (g0, then g2)
  float* buf2  = buf1 + (size_t)N * 128;  // N*128  (a0, then h2)
  float* buf3  = buf2 + (size_t)N * 128;  // N*256  (h1, then g3)

  hipMemsetAsync(cnt, 0, (size_t)2 * N * sizeof(int), stream);  // cnt + cur

  const int gE = (E + 255) / 256;
  const int gN = (N + 255) / 256;
  const int gRows = (N + 63) / 64;     // gemm blocks (64 rows each)
  const int gWave = (N + 3) / 4;       // agg blocks (4 waves each)

  // CSR build (shared by all three convs)
  k_count<<<gE, 256, 0, stream>>>(dst, cnt, E);
  k_dis<<<gN, 256, 0, stream>>>(cnt, dis, N);
  k_scan<<<1, 1024, 0, stream>>>(cnt, offs, N, E);
  k_fill<<<gE, 256, 0, stream>>>(src, dst, offs, cur, esrc, E);

  // g0 = dis .* lrelu(x @ W_in + b_in)
  k_gemm<128, 128, 0><<<gRows, 256, 0, stream>>>(x, W_in, b_in, dis, buf1, N);
  // a0 = A h0
  k_agg128<0><<<gWave, 256, 0, stream>>>(buf1, esrc, offs, dis, nullptr, buf2, N);
  // h1 = lrelu(a0 @ W1 + b1)
  k_gemm<128, 256, 1><<<gRows, 256, 0, stream>>>(buf2, W1, b1, nullptr, buf3, N);
  // g2 = dis .* (h1 @ W2)
  k_gemm<256, 128, 2><<<gRows, 256, 0, stream>>>(buf3, W2, nullptr, dis, buf1, N);
  // h2 = lrelu(A-agg(g2) + b2)
  k_agg128<1><<<gWave, 256, 0, stream>>>(buf1, esrc, offs, dis, b2, buf2, N);
  // g3 = dis .* (h2 @ W3)
  k_gemm<128, 64, 2><<<gRows, 256, 0, stream>>>(buf2, W3, nullptr, dis, buf3, N);
  // out = lrelu(A-agg(g3) + b3) @ W_out + b_out
  k_agg_final<<<gWave, 256, 0, stream>>>(buf3, esrc, offs, dis, b3, W_out, b_out,
                                         out, N);
}